// Round 4
// baseline (715.890 us; speedup 1.0000x reference)
//
#include <hip/hip_runtime.h>
#include <hip/hip_bf16.h>
#include <math.h>

#define TT 1024
#define KK 128
#define BB 512
#define TPB 512
#define MINV -100000.0f

typedef float v2f __attribute__((ext_vector_type(2)));

// One block per batch row, 512 threads (8 waves).
// Thread (to = tid>>2, q = tid&3) owns E[to][q*32 .. q*32+31] in 32 VGPRs
// (16 v2f) -- small enough that the register allocator cannot spill it.
// Per step (ONE barrier):
//   p[to] = exp(a - m) -> LDS (q==0 lanes store); thread 0 publishes a (next m)
//   barrier
//   partial = sum_{frm in quarter} E*p ; s = quartet-combine via 2 shfl_xor
//   a = log(s) + m + feat[t][to]
// m is a stale-by-one offset: cancels exactly in log(s)+m, fp32-safe.
__global__ __launch_bounds__(TPB, 4)
void crf_fwd_kernel(const float* __restrict__ feats,
                    const float* __restrict__ trans,
                    float* __restrict__ out)
{
    const int b    = blockIdx.x;
    const int tid  = threadIdx.x;
    const int to   = tid >> 2;      // 0..127 output tag
    const int q    = tid & 3;       // frm quarter
    const int lane = tid & 63;
    const int wv   = tid >> 6;      // 0..7

    __shared__ __align__(16) float p_lds[2][KK];
    __shared__ float mslot[2];
    __shared__ float wred[8];
    __shared__ float sred[8];

    // ---- E quarter-row in registers: frm in [q*32, q*32+32) ----
    v2f E2[16];
    {
        const float4* tr = reinterpret_cast<const float4*>(trans + to * KK + q * 32);
        #pragma unroll
        for (int i = 0; i < 8; ++i) {
            float4 v = tr[i];
            E2[2 * i + 0] = v2f{__expf(v.x), __expf(v.y)};
            E2[2 * i + 1] = v2f{__expf(v.z), __expf(v.w)};
        }
    }
    const float tEnd = trans[(KK - 2) * KK + to];

    // 2-deep feat prefetch
    const float* fp = feats + (size_t)b * TT * KK + to;
    float f0 = fp[0];
    float f1 = fp[KK];
    fp += 2 * KK;

    float a = (to == KK - 1) ? 0.0f : MINV;  // alpha_0
    float m = 0.0f;

    for (int t = 0; t < TT; ++t) {
        const int buf = t & 1;

        float f2 = 0.0f;
        if (t + 2 < TT) f2 = *fp;
        fp += KK;

        if (tid == 0) mslot[buf] = a;       // publish alpha_t[0] = next m
        const float pv = __expf(a - m);
        if (q == 0) p_lds[buf][to] = pv;
        __syncthreads();                    // the ONE barrier per step

        const float m_next = (t == 0) ? 0.0f : mslot[buf];

        // ---- partial dot over this thread's 32 frm ----
        const float4* p4 = reinterpret_cast<const float4*>(&p_lds[buf][q * 32]);
        v2f acc0 = {0.f,0.f}, acc1 = {0.f,0.f}, acc2 = {0.f,0.f}, acc3 = {0.f,0.f};
        #pragma unroll
        for (int i = 0; i < 2; ++i) {
            float4 pa = p4[4*i+0], pb = p4[4*i+1], pc = p4[4*i+2], pd = p4[4*i+3];
            acc0 = __builtin_elementwise_fma(E2[8*i+0], v2f{pa.x, pa.y}, acc0);
            acc1 = __builtin_elementwise_fma(E2[8*i+1], v2f{pa.z, pa.w}, acc1);
            acc2 = __builtin_elementwise_fma(E2[8*i+2], v2f{pb.x, pb.y}, acc2);
            acc3 = __builtin_elementwise_fma(E2[8*i+3], v2f{pb.z, pb.w}, acc3);
            acc0 = __builtin_elementwise_fma(E2[8*i+4], v2f{pc.x, pc.y}, acc0);
            acc1 = __builtin_elementwise_fma(E2[8*i+5], v2f{pc.z, pc.w}, acc1);
            acc2 = __builtin_elementwise_fma(E2[8*i+6], v2f{pd.x, pd.y}, acc2);
            acc3 = __builtin_elementwise_fma(E2[8*i+7], v2f{pd.z, pd.w}, acc3);
        }
        v2f accA = acc0 + acc1;
        v2f accB = acc2 + acc3;
        v2f accT = accA + accB;
        float sq = accT.x + accT.y;
        // combine quartet partials (lanes differing in bits 0,1 = same to)
        sq += __shfl_xor(sq, 1, 64);
        sq += __shfl_xor(sq, 2, 64);

        a = __logf(sq) + m + f0;   // log(0) -> -inf for START tag: 0-weight
        f0 = f1; f1 = f2;
        m = m_next;
    }

    // ---- out[b] = logsumexp_to(alpha[to] + trans[END][to]) ----
    const float fin = a + tEnd;   // quadruplicated across q
    float wm = fin;
    #pragma unroll
    for (int s = 32; s >= 1; s >>= 1)
        wm = fmaxf(wm, __shfl_xor(wm, s, 64));
    if (lane == 0) wred[wv] = wm;
    __syncthreads();
    float M = wred[0];
    #pragma unroll
    for (int i = 1; i < 8; ++i) M = fmaxf(M, wred[i]);

    float e = (q == 0) ? __expf(fin - M) : 0.0f;   // count each tag once
    #pragma unroll
    for (int s = 32; s >= 1; s >>= 1)
        e += __shfl_xor(e, s, 64);
    if (lane == 0) sred[wv] = e;
    __syncthreads();
    if (tid == 0) {
        float S = sred[0];
        #pragma unroll
        for (int i = 1; i < 8; ++i) S += sred[i];
        out[b] = M + __logf(S);
    }
}

extern "C" void kernel_launch(void* const* d_in, const int* in_sizes, int n_in,
                              void* d_out, int out_size, void* d_ws, size_t ws_size,
                              hipStream_t stream) {
    const float* feats = (const float*)d_in[0];  // [B, T, K] f32
    const float* trans = (const float*)d_in[1];  // [K, K] f32
    float* out = (float*)d_out;                  // [B] f32

    crf_fwd_kernel<<<BB, TPB, 0, stream>>>(feats, trans, out);
}

// Round 5
// 475.595 us; speedup vs baseline: 1.5053x; 1.5053x over previous
//
#include <hip/hip_runtime.h>
#include <hip/hip_bf16.h>
#include <math.h>

#define TT 1024
#define KK 128
#define BB 512
#define TPB 256
#define MINV -100000.0f

typedef float v2f __attribute__((ext_vector_type(2)));

// pad 4 floats per 16: slice o starts at float 20*o -> bank 20*o%32, all 8
// octets hit distinct bank-quads => conflict-free broadcast b128 reads.
__device__ __forceinline__ int padidx(int f) { return f + ((f >> 4) << 2); }

// 512 blocks (1 per batch row) x 256 threads (4 waves).
// Thread (g=tid>>3, o=tid&7) owns E[g*4 .. g*4+3][o*16 .. o*16+15] in 64 VGPRs.
// Per step (ONE barrier):
//   pv = exp(a - m); o<4 lanes write p (padded layout); tid0 publishes a
//   barrier
//   each thread: 4x ds_read_b128 (64B), 32 pk_fma -> 4 row-partials
//   exchange-split butterfly (4 shfls) -> thread owns full sum for to=g*4+rr
//   a = log(s) + m + feat[t][to]
// m = alpha_{t-1}[0] (stale-by-one offset): cancels exactly in log(s)+m.
__global__ __launch_bounds__(TPB, 2)
void crf_fwd_kernel(const float* __restrict__ feats,
                    const float* __restrict__ trans,
                    float* __restrict__ out)
{
    const int b    = blockIdx.x;
    const int tid  = threadIdx.x;
    const int g    = tid >> 3;          // 0..31 row group
    const int o    = tid & 7;           // frm octet slice
    const int rr   = ((o & 1) << 1) | ((o >> 1) & 1);
    const int to_out = (g << 2) + rr;   // the tag this thread finalizes
    const int lane = tid & 63;
    const int wv   = tid >> 6;          // 0..3

    __shared__ __align__(16) float p_lds[2][160];
    __shared__ float mslot[2];
    __shared__ float wred[4];
    __shared__ float sred[4];

    // ---- E tile in registers: rows g*4+r, frm slice [o*16, o*16+16) ----
    v2f E2[4][8];
    #pragma unroll
    for (int r = 0; r < 4; ++r) {
        const float4* tr = reinterpret_cast<const float4*>(trans + (g * 4 + r) * KK + o * 16);
        #pragma unroll
        for (int i = 0; i < 4; ++i) {
            float4 v = tr[i];
            E2[r][2 * i + 0] = v2f{__expf(v.x), __expf(v.y)};
            E2[r][2 * i + 1] = v2f{__expf(v.z), __expf(v.w)};
        }
    }
    const float tEnd = trans[(KK - 2) * KK + to_out];

    // 2-deep feat prefetch (dup across o>=4 partner, same address -> coalesced)
    const float* fp = feats + (size_t)b * TT * KK + to_out;
    float f0 = fp[0];
    float f1 = fp[KK];
    fp += 2 * KK;

    float a = (to_out == KK - 1) ? 0.0f : MINV;  // alpha_0 (START = K-1)
    float m = 0.0f;

    for (int t = 0; t < TT; ++t) {
        const int buf = t & 1;

        float f2 = 0.0f;
        if (t + 2 < TT) f2 = *fp;
        fp += KK;

        if (tid == 0) mslot[buf] = a;            // to_out==0 is tid 0
        const float pv = __expf(a - m);
        if (o < 4) p_lds[buf][padidx(to_out)] = pv;
        __syncthreads();                         // the ONE barrier per step

        const float m_next = (t == 0) ? 0.0f : mslot[buf];

        // ---- partial dots: 4 rows x 16 frm from 64B of LDS ----
        const float* pbase = &p_lds[buf][o * 20];
        v2f acc0 = {0.f,0.f}, acc1 = {0.f,0.f}, acc2 = {0.f,0.f}, acc3 = {0.f,0.f};
        #pragma unroll
        for (int i = 0; i < 4; ++i) {
            float4 pq = *reinterpret_cast<const float4*>(pbase + i * 4);
            v2f plo = v2f{pq.x, pq.y};
            v2f phi = v2f{pq.z, pq.w};
            acc0 = __builtin_elementwise_fma(E2[0][2 * i], plo, acc0);
            acc1 = __builtin_elementwise_fma(E2[1][2 * i], plo, acc1);
            acc2 = __builtin_elementwise_fma(E2[2][2 * i], plo, acc2);
            acc3 = __builtin_elementwise_fma(E2[3][2 * i], plo, acc3);
            acc0 = __builtin_elementwise_fma(E2[0][2 * i + 1], phi, acc0);
            acc1 = __builtin_elementwise_fma(E2[1][2 * i + 1], phi, acc1);
            acc2 = __builtin_elementwise_fma(E2[2][2 * i + 1], phi, acc2);
            acc3 = __builtin_elementwise_fma(E2[3][2 * i + 1], phi, acc3);
        }
        float s0 = acc0.x + acc0.y;
        float s1 = acc1.x + acc1.y;
        float s2 = acc2.x + acc2.y;
        float s3 = acc3.x + acc3.y;

        // ---- exchange-split combine over the 8 octet lanes (4 shfls) ----
        // r1 (xor 1): even o keeps rows {0,1}, odd keeps {2,3}
        float send_lo = (o & 1) ? s0 : s2;
        float send_hi = (o & 1) ? s1 : s3;
        float recv_lo = __shfl_xor(send_lo, 1, 64);
        float recv_hi = __shfl_xor(send_hi, 1, 64);
        float qa = ((o & 1) ? s2 : s0) + recv_lo;  // row (o&1)*2 + 0
        float qb = ((o & 1) ? s3 : s1) + recv_hi;  // row (o&1)*2 + 1
        // r2 (xor 2): o&2==0 keeps qa, o&2 keeps qb
        float send2 = (o & 2) ? qa : qb;
        float recv2 = __shfl_xor(send2, 2, 64);
        float sv = ((o & 2) ? qb : qa) + recv2;    // row rr over half span
        // r3 (xor 4): both partners hold same row, complementary spans
        sv += __shfl_xor(sv, 4, 64);               // full 128-frm sum

        a = __logf(sv) + m + f0;   // log(0) -> -inf for START tag: 0-weight
        f0 = f1; f1 = f2;
        m = m_next;
    }

    // ---- out[b] = logsumexp_to(alpha[to] + trans[END][to]) ----
    const float fin = a + tEnd;       // duplicated on o>=4 partner
    float wm = fin;
    #pragma unroll
    for (int s = 32; s >= 1; s >>= 1)
        wm = fmaxf(wm, __shfl_xor(wm, s, 64));
    if (lane == 0) wred[wv] = wm;
    __syncthreads();
    float M = fmaxf(fmaxf(wred[0], wred[1]), fmaxf(wred[2], wred[3]));

    float e = (o < 4) ? __expf(fin - M) : 0.0f;   // count each tag once
    #pragma unroll
    for (int s = 32; s >= 1; s >>= 1)
        e += __shfl_xor(e, s, 64);
    if (lane == 0) sred[wv] = e;
    __syncthreads();
    if (tid == 0)
        out[b] = M + __logf(((sred[0] + sred[1]) + (sred[2] + sred[3])));
}

extern "C" void kernel_launch(void* const* d_in, const int* in_sizes, int n_in,
                              void* d_out, int out_size, void* d_ws, size_t ws_size,
                              hipStream_t stream) {
    const float* feats = (const float*)d_in[0];  // [B, T, K] f32
    const float* trans = (const float*)d_in[1];  // [K, K] f32
    float* out = (float*)d_out;                  // [B] f32

    crf_fwd_kernel<<<BB, TPB, 0, stream>>>(feats, trans, out);
}

// Round 6
// 382.732 us; speedup vs baseline: 1.8705x; 1.2426x over previous
//
#include <hip/hip_runtime.h>
#include <hip/hip_bf16.h>
#include <math.h>

#define TT 1024
#define KK 128
#define BB 512
#define TPB 256

typedef float v2f __attribute__((ext_vector_type(2)));

// pad 4 floats per 16: slice o starts at float 20*o -> distinct banks, and
// 20*o*4B is 16B-aligned (80*o). Verified conflict-free in R5 (SQ_LDS_BANK_CONFLICT=0).
__device__ __forceinline__ int padidx(int f) { return f + ((f >> 4) << 2); }

// VALU-latency cross-lane via DPP (replaces ~120-cyc DS-pipe shuffles).
template <int CTRL>
__device__ __forceinline__ float dppf(float x) {
    union { float f; int i; } u, o;
    u.f = x;
    o.i = __builtin_amdgcn_update_dpp(0, u.i, CTRL, 0xF, 0xF, false);
    return o.f;
}
#define DPP_XOR1 0xB1   // quad_perm [1,0,3,2]  : lane ^= 1
#define DPP_XOR2 0x4E   // quad_perm [2,3,0,1]  : lane ^= 2
#define DPP_XOR8 0x128  // row_ror:8            : lane ^= 8 (within 16-lane row)

// Scaled CRF forward (exp-space, no exp/log on the serial chain):
//   v_{t+1} = (E . v_t) * exp(feat_t) * r_t,  r_t = rcp(v_t[tag0]) (published
//   via LDS one step earlier),  La accumulates -log(r_t) (off-chain).
// 512 blocks x 256 threads. Thread layout: lane bits {0,1,3} = frm-slice o,
// bits {2,4,5}+wave = tag-group g. Thread owns E[g*4..g*4+3][o*16..o*16+16).
// Per step (ONE barrier): ds_read v (4x b128) -> 32 pk_fma -> 3 DPP folds ->
// v' = u*ef*r -> ds_write v' -> barrier.
__global__ __launch_bounds__(TPB, 2)
void crf_fwd_kernel(const float* __restrict__ feats,
                    const float* __restrict__ trans,
                    float* __restrict__ out)
{
    const int b    = blockIdx.x;
    const int tid  = threadIdx.x;
    const int lane = tid & 63;
    const int wave = tid >> 6;
    const int o    = (lane & 3) | (((lane >> 3) & 1) << 2);           // slice
    const int g    = ((lane >> 2) & 1) | (((lane >> 4) & 3) << 1) | (wave << 3);
    const int rr   = ((o & 1) << 1) | ((o >> 1) & 1);
    const int tag  = (g << 2) + rr;       // tag finalized here (dup over o&4)
    const bool wr  = (o & 4) == 0;        // writer copy of the dup pair

    __shared__ __align__(16) float v_lds[2][160];
    __shared__ float rslot[2];
    __shared__ float sred[4];

    // ---- E tile: rows g*4+r, frm slice [o*16, o*16+16) : 64 floats ----
    v2f E2[4][8];
    #pragma unroll
    for (int r = 0; r < 4; ++r) {
        const float4* tr = reinterpret_cast<const float4*>(trans + (g * 4 + r) * KK + o * 16);
        #pragma unroll
        for (int i = 0; i < 4; ++i) {
            float4 v = tr[i];
            E2[r][2 * i + 0] = v2f{__expf(v.x), __expf(v.y)};
            E2[r][2 * i + 1] = v2f{__expf(v.z), __expf(v.w)};
        }
    }
    const float eEnd = __expf(trans[(KK - 2) * KK + tag]);

    // feat pipeline: at iter t, ef = exp(feat[t]), fA = feat[t+1], fp -> feat[t+2]
    const float* fp = feats + (size_t)b * TT * KK + tag;
    float f0 = fp[0];
    float fA = fp[KK];
    fp += 2 * KK;
    float ef = __expf(f0);

    // init: v_0 = e_START (START = K-1), r_0 = 1
    if (tid == 0) rslot[0] = 1.0f;
    if (wr) v_lds[0][padidx(tag)] = (tag == KK - 1) ? 1.0f : 0.0f;
    __syncthreads();

    float La = 0.0f;   // -sum log r_t (uniform across threads)
    float vv = 0.0f;   // this thread's v_T[tag] after the loop

    for (int t = 0; t < TT; ++t) {
        const int buf = t & 1;

        // ---- off-chain work: next feat load + next exp(feat) ----
        float fC = 0.0f;
        if (t + 2 < TT) fC = *fp;
        fp += KK;
        const float ef_next = __expf(fA);

        const float r = rslot[buf];        // published last step (ordered by barrier)

        // ---- u partials: 4 rows x 16 frm from 64 B of LDS ----
        const float* pbase = &v_lds[buf][o * 20];
        v2f acc0 = {0.f,0.f}, acc1 = {0.f,0.f}, acc2 = {0.f,0.f}, acc3 = {0.f,0.f};
        #pragma unroll
        for (int i = 0; i < 4; ++i) {
            float4 pq = *reinterpret_cast<const float4*>(pbase + i * 4);
            v2f plo = v2f{pq.x, pq.y};
            v2f phi = v2f{pq.z, pq.w};
            acc0 = __builtin_elementwise_fma(E2[0][2 * i], plo, acc0);
            acc1 = __builtin_elementwise_fma(E2[1][2 * i], plo, acc1);
            acc2 = __builtin_elementwise_fma(E2[2][2 * i], plo, acc2);
            acc3 = __builtin_elementwise_fma(E2[3][2 * i], plo, acc3);
            acc0 = __builtin_elementwise_fma(E2[0][2 * i + 1], phi, acc0);
            acc1 = __builtin_elementwise_fma(E2[1][2 * i + 1], phi, acc1);
            acc2 = __builtin_elementwise_fma(E2[2][2 * i + 1], phi, acc2);
            acc3 = __builtin_elementwise_fma(E2[3][2 * i + 1], phi, acc3);
        }
        float s0 = acc0.x + acc0.y;
        float s1 = acc1.x + acc1.y;
        float s2 = acc2.x + acc2.y;
        float s3 = acc3.x + acc3.y;

        // ---- exchange-split combine on lane bits {0,1,3} via DPP ----
        float send_lo = (o & 1) ? s0 : s2;
        float send_hi = (o & 1) ? s1 : s3;
        float recv_lo = dppf<DPP_XOR1>(send_lo);
        float recv_hi = dppf<DPP_XOR1>(send_hi);
        float qa = ((o & 1) ? s2 : s0) + recv_lo;   // row 2*(o&1) over 2 slices
        float qb = ((o & 1) ? s3 : s1) + recv_hi;   // row 2*(o&1)+1
        float send2 = (o & 2) ? qa : qb;
        float recv2 = dppf<DPP_XOR2>(send2);
        float sv = ((o & 2) ? qb : qa) + recv2;     // row rr over 4 slices
        sv += dppf<DPP_XOR8>(sv);                   // full u[tag]

        // ---- v' = u * ef * r ; bookkeeping off-chain ----
        vv = sv * ef * r;
        La -= __logf(r);                            // uniform; thread0's value used

        if (tid == 0) rslot[buf ^ 1] = __builtin_amdgcn_rcpf(vv);  // r for t+1
        if (wr) v_lds[buf ^ 1][padidx(tag)] = vv;

        __syncthreads();                            // the ONE barrier per step

        ef = ef_next;
        fA = fC;
    }

    // ---- out[b] = La + log( sum_tag v_T[tag] * exp(trans[END][tag]) ) ----
    float e = wr ? vv * eEnd : 0.0f;
    #pragma unroll
    for (int s = 32; s >= 1; s >>= 1)
        e += __shfl_xor(e, s, 64);
    if (lane == 0) sred[wave] = e;
    __syncthreads();
    if (tid == 0)
        out[b] = La + __logf((sred[0] + sred[1]) + (sred[2] + sred[3]));
}

extern "C" void kernel_launch(void* const* d_in, const int* in_sizes, int n_in,
                              void* d_out, int out_size, void* d_ws, size_t ws_size,
                              hipStream_t stream) {
    const float* feats = (const float*)d_in[0];  // [B, T, K] f32
    const float* trans = (const float*)d_in[1];  // [K, K] f32
    float* out = (float*)d_out;                  // [B] f32

    crf_fwd_kernel<<<BB, TPB, 0, stream>>>(feats, trans, out);
}